// Round 10
// baseline (261.846 us; speedup 1.0000x reference)
//
#include <hip/hip_runtime.h>
#include <hip/hip_bf16.h>
#include <math.h>

#define D_    256
#define NT_   8192
#define NN_   512
#define B_    16
#define H_    8
#define EPG_  16384
#define BN_EPS 1e-5f

typedef __attribute__((ext_vector_type(8))) short bx8;
typedef __attribute__((ext_vector_type(4))) short sx4;
typedef __attribute__((ext_vector_type(4))) float fx4;

__device__ __forceinline__ float gelu_exact(float x) {
    return 0.5f * x * (1.0f + erff(x * 0.70710678118654752f));
}
__device__ __forceinline__ short bf16s(float v) {
    __hip_bfloat16 hb = __float2bfloat16(v);
    return *(short*)&hb;
}

// async global->LDS 16B per lane; lds dest wave-uniform base, gsrc per-lane
typedef __attribute__((address_space(1))) const unsigned int GU;
typedef __attribute__((address_space(3))) unsigned int LU;
__device__ __forceinline__ void gl_lds16(const void* g, void* l) {
    __builtin_amdgcn_global_load_lds((GU*)g, (LU*)l, 16, 0, 0);
}

// ============ bf16 MFMA GEMM: C = A(MxK) @ B(NxK)^T (+bias)(+epi) =========
// Full-K-chunk staging (KCH=256): ONE stage burst + ONE barrier per 256-K
// chunk, then an unbroken 32-ds_read/32-MFMA run. LDS 64KB -> 2 blocks/CU;
// cross-block overlap hides the single load stall. 16B slots XOR-swizzled
// by (row&7) on BOTH sides (pre-swizzled global src for linear
// global_load_lds dest + same XOR on ds_read slot).
// EPI: 0 none, 1 gelu, 2 resid+BN, 3 resid+gelu(acc)+BN,
//      4 transposed-write: cols>=sR packed-4 to Tout(=resid), cols<sR -> Cout
// OBF: output bf16 (else f32). RBF: resid bf16 (else f32).
template<int TM, int TN, int EPI, int OBF, int RBF>
__global__ __launch_bounds__(256)
void mgemm(const short* __restrict__ A, const short* __restrict__ Bw,
           const float* __restrict__ bias, void* __restrict__ Cout,
           int M, int N, int K,
           long sA, long sB, long sC, long sR,
           const void* __restrict__ resid,
           const float* __restrict__ bng, const float* __restrict__ bnb,
           const float* __restrict__ bnm, const float* __restrict__ bnv)
{
    constexpr int MR = TM / 32, NR = TN / 32;   // per-wave 16x16 frags
    constexpr int NIA = TM / 2, NIB = TN / 2;   // 1KiB issues (2 rows each)
    __shared__ short As[TM][256];
    __shared__ short Bs[TN][256];
    const int bz = blockIdx.z;
    A  += (size_t)bz * sA;
    Bw += (size_t)bz * sB;
    const int bm = blockIdx.y * TM, bn = blockIdx.x * TN;
    const int tid = threadIdx.x;
    const int w = tid >> 6, lane = tid & 63;
    const int wm = w >> 1, wn = w & 1;
    const int fr = lane & 15, hi = lane >> 4;
    const int rli = lane >> 5;                 // row within 1KiB issue (0/1)
    const int sl  = lane & 31;                 // physical 16B slot
    fx4 acc[MR][NR] = {};

    auto STAGE = [&](int kc) {
        #pragma unroll
        for (int i = w; i < NIA + NIB; i += 4) {
            if (i < NIA) {
                const int row = i * 2 + rli;
                gl_lds16(A + (size_t)(bm + row) * K + kc + ((sl ^ (row & 7)) << 3),
                         (char*)As + i * 1024);
            } else {
                const int j = i - NIA;
                const int row = j * 2 + rli;
                gl_lds16(Bw + (size_t)(bn + row) * K + kc + ((sl ^ (row & 7)) << 3),
                         (char*)Bs + j * 1024);
            }
        }
    };

    const int NC = K >> 8;
    for (int c = 0; c < NC; ++c) {
        if (c) __syncthreads();                 // prior chunk's reads done
        STAGE(c << 8);
        __syncthreads();                        // drain loads (vmcnt0 at barrier)
        #pragma unroll
        for (int ks = 0; ks < 8; ++ks) {
            bx8 af[MR], bf[NR];
            #pragma unroll
            for (int m = 0; m < MR; ++m) {
                const int row = wm * (TM / 2) + m * 16 + fr;
                af[m] = *(const bx8*)&As[row][((((ks << 2) | hi) ^ (row & 7)) << 3)];
            }
            #pragma unroll
            for (int n = 0; n < NR; ++n) {
                const int row = wn * (TN / 2) + n * 16 + fr;
                bf[n] = *(const bx8*)&Bs[row][((((ks << 2) | hi) ^ (row & 7)) << 3)];
            }
            #pragma unroll
            for (int m = 0; m < MR; ++m)
                #pragma unroll
                for (int n = 0; n < NR; ++n)
                    acc[m][n] = __builtin_amdgcn_mfma_f32_16x16x32_bf16(af[m], bf[n], acc[m][n], 0, 0, 0);
        }
    }

    float* Cf = (float*)Cout + (size_t)bz * sC;
    __hip_bfloat16* Cb = (__hip_bfloat16*)Cout + (size_t)bz * sC;
    const float* Rf = (const float*)resid + ((EPI == 2 || EPI == 3) ? (size_t)bz * sR : 0);
    const __hip_bfloat16* Rb = (const __hip_bfloat16*)resid + ((EPI == 2 || EPI == 3) ? (size_t)bz * sR : 0);
    #pragma unroll
    for (int m = 0; m < MR; ++m) {
        #pragma unroll
        for (int n = 0; n < NR; ++n) {
            const int gm0 = bm + wm * (TM / 2) + m * 16 + hi * 4;
            const int gn  = bn + wn * (TN / 2) + n * 16 + fr;
            float vv[4];
            #pragma unroll
            for (int r = 0; r < 4; ++r) {
                const int gm = gm0 + r;
                float v = acc[m][n][r];
                if (bias) v += bias[gn];
                if (EPI == 1) v = gelu_exact(v);
                if (EPI == 2 || EPI == 3) {
                    const float rv = RBF ? __bfloat162float(Rb[(size_t)gm * N + gn])
                                         : Rf[(size_t)gm * N + gn];
                    if (EPI == 2) v += rv;
                    else          v = rv + gelu_exact(v);
                    v = (v - bnm[gn]) * (bng[gn] * rsqrtf(bnv[gn] + BN_EPS)) + bnb[gn];
                }
                vv[r] = v;
            }
            if (EPI == 4) {
                const int tc = (int)sR;             // transpose cutoff column
                if (gn >= tc) {
                    short* Tout = (short*)resid;
                    sx4 pk;
                    #pragma unroll
                    for (int r = 0; r < 4; ++r) pk[r] = bf16s(vv[r]);
                    *(sx4*)(Tout + ((size_t)((gm0 >> 9) * (N - tc) + (gn - tc))) * 512 + (gm0 & 511)) = pk;
                } else {
                    #pragma unroll
                    for (int r = 0; r < 4; ++r)
                        Cb[(size_t)(gm0 + r) * N + gn] = __float2bfloat16(vv[r]);
                }
            } else {
                #pragma unroll
                for (int r = 0; r < 4; ++r) {
                    if (OBF) Cb[(size_t)(gm0 + r) * N + gn] = __float2bfloat16(vv[r]);
                    else     Cf[(size_t)(gm0 + r) * N + gn] = vv[r];
                }
            }
        }
    }
}

// ============ converts ======================================================
__device__ __forceinline__ void cv4(const float4 v, __hip_bfloat16* d) {
    __hip_bfloat162* dp = (__hip_bfloat162*)d;
    dp[0] = __hip_bfloat162(__float2bfloat16(v.x), __float2bfloat16(v.y));
    dp[1] = __hip_bfloat162(__float2bfloat16(v.z), __float2bfloat16(v.w));
}

__global__ __launch_bounds__(256)
void conv6(const float* __restrict__ x,  const float* __restrict__ wg,
           const float* __restrict__ iw, const float* __restrict__ ow,
           const float* __restrict__ w1, const float* __restrict__ w2,
           __hip_bfloat16* xb, __hip_bfloat16* wgb, __hip_bfloat16* iwb,
           __hip_bfloat16* owb, __hip_bfloat16* w1b, __hip_bfloat16* w2b)
{
    int i = blockIdx.x * 256 + threadIdx.x;   // float4 index
    const float* s; __hip_bfloat16* d; int o;
    if      (i < 524288) { s = x;  d = xb;  o = i; }
    else if (i < 540672) { s = wg; d = wgb; o = i - 524288; }
    else if (i < 589824) { s = iw; d = iwb; o = i - 540672; }
    else if (i < 606208) { s = ow; d = owb; o = i - 589824; }
    else if (i < 671744) { s = w1; d = w1b; o = i - 606208; }
    else                 { s = w2; d = w2b; o = i - 671744; }
    cv4(((const float4*)s)[o], d + (size_t)o * 4);
}

__global__ __launch_bounds__(256)
void convA(const float* __restrict__ s, __hip_bfloat16* __restrict__ d, int n4)
{
    int i = blockIdx.x * 256 + threadIdx.x;
    if (i >= n4) return;
    cv4(((const float4*)s)[i], d + (size_t)i * 4);
}

// ============ dense adjacency build ========================================
__global__ __launch_bounds__(256)
void build_S(const int* __restrict__ rows, const int* __restrict__ cols,
             const float* __restrict__ vals, float* __restrict__ SA)
{
    const int e = blockIdx.x * 256 + threadIdx.x;   // 262144 edges
    const int r = rows[e], c = cols[e];
    const int g = r >> 9;
    atomicAdd(&SA[((size_t)g << 18) + (size_t)(r & 511) * 512 + (c - (g << 9))], vals[e]);
}

// ============ MFMA flash attention: block = (b, h, 64 q-rows) ==============
// Zero-barrier / zero-staging: K and V fragments read directly from global
// (L2-resident 64KB slab per (b,h), shared by 8 q-tile blocks via XCD
// swizzle). Only LDS use is the wave-local P buffer -> 65KB -> 2 blocks/CU.
__global__ __launch_bounds__(256, 2)
void attn_mfma(const short* __restrict__ qkv, const short* __restrict__ VtG,
               __hip_bfloat16* __restrict__ ctx)
{
    const int swz = (blockIdx.x & 7) * 128 + (blockIdx.x >> 3);
    const int qt = swz & 7;
    const int h  = (swz >> 3) & 7;
    const int b  = swz >> 6;
    __shared__ short Ps[64][520];
    const int tid = threadIdx.x;
    const int lane = tid & 63, wq = tid >> 6;
    const short* base = qkv + (size_t)b * NN_ * 768;
    const short* kb_  = base + 256 + h * 32;
    const short* vtb  = VtG + (size_t)(b * 8 + h) * 32 * 512;

    const int fr = lane & 15, hi = lane >> 4, fk = hi << 3;
    const int qrow = qt * 64 + wq * 16 + fr;
    bx8 qf = *(const bx8*)(base + (size_t)qrow * 768 + h * 32 + fk);

    // S^T tiles: sc[nt] = mfma(K_frag, Q) -> lane holds q=fr, keys nt*16+hi*4+r
    fx4 sc[32];
    #pragma unroll
    for (int nt = 0; nt < 32; ++nt) {
        bx8 kf = *(const bx8*)(kb_ + (size_t)(nt * 16 + fr) * 768 + fk);
        fx4 z = {0.f, 0.f, 0.f, 0.f};
        sc[nt] = __builtin_amdgcn_mfma_f32_16x16x32_bf16(kf, qf, z, 0, 0, 0);
    }

    const float scale = 0.17677669529663687f;   // 1/sqrt(32)
    float mx = -1e30f;
    #pragma unroll
    for (int nt = 0; nt < 32; ++nt)
        mx = fmaxf(mx, fmaxf(fmaxf(sc[nt][0], sc[nt][1]), fmaxf(sc[nt][2], sc[nt][3])));
    mx = fmaxf(mx, __shfl_xor(mx, 16, 64));
    mx = fmaxf(mx, __shfl_xor(mx, 32, 64));
    const float M = mx * scale;
    float s = 0.f;
    #pragma unroll
    for (int nt = 0; nt < 32; ++nt) {
        #pragma unroll
        for (int r = 0; r < 4; ++r) {
            const float p = __expf(sc[nt][r] * scale - M);
            sc[nt][r] = p;
            s += p;
        }
    }
    s += __shfl_xor(s, 16, 64);
    s += __shfl_xor(s, 32, 64);
    const float inv = 1.0f / s;
    {   // P -> LDS: 4 consecutive keys per tile -> one 8B write (wave-local)
        const int q = wq * 16 + fr;
        const int kb2 = hi << 2;
        #pragma unroll
        for (int nt = 0; nt < 32; ++nt) {
            sx4 pk;
            #pragma unroll
            for (int r = 0; r < 4; ++r) pk[r] = bf16s(sc[nt][r] * inv);
            *(sx4*)&Ps[q][nt * 16 + kb2] = pk;
        }
    }

    // O = P @ V : pf from LDS, vf direct from global V^T
    fx4 oacc[2] = {};
    #pragma unroll
    for (int step = 0; step < 16; ++step) {
        bx8 pf = *(const bx8*)&Ps[wq * 16 + fr][step * 32 + fk];
        #pragma unroll
        for (int nt = 0; nt < 2; ++nt) {
            bx8 vf = *(const bx8*)(vtb + (size_t)(nt * 16 + fr) * 512 + step * 32 + fk);
            oacc[nt] = __builtin_amdgcn_mfma_f32_16x16x32_bf16(pf, vf, oacc[nt], 0, 0, 0);
        }
    }
    #pragma unroll
    for (int nt = 0; nt < 2; ++nt) {
        #pragma unroll
        for (int r = 0; r < 4; ++r) {
            const int q = qt * 64 + wq * 16 + hi * 4 + r;
            const int d = nt * 16 + fr;
            ctx[(size_t)(b * NN_ + q) * D_ + h * 32 + d] = __float2bfloat16(oacc[nt][r]);
        }
    }
}

extern "C" void kernel_launch(void* const* d_in, const int* in_sizes, int n_in,
                              void* d_out, int out_size, void* d_ws, size_t ws_size,
                              hipStream_t stream) {
    const float* x      = (const float*)d_in[0];
    const int*   erows  = (const int*)d_in[1];
    const int*   ecols  = (const int*)d_in[2];
    const float* evals  = (const float*)d_in[3];
    const float* w_gcn  = (const float*)d_in[4];
    const float* in_w   = (const float*)d_in[5];
    const float* in_b   = (const float*)d_in[6];
    const float* outw   = (const float*)d_in[7];
    const float* outb   = (const float*)d_in[8];
    const float* w1     = (const float*)d_in[9];
    const float* b1     = (const float*)d_in[10];
    const float* w2     = (const float*)d_in[11];
    const float* b2     = (const float*)d_in[12];
    const float* bn1g = (const float*)d_in[15], *bn1b = (const float*)d_in[16];
    const float* bn1m = (const float*)d_in[17], *bn1v = (const float*)d_in[18];
    const float* bn2g = (const float*)d_in[19], *bn2b = (const float*)d_in[20];
    const float* bn2m = (const float*)d_in[21], *bn2v = (const float*)d_in[22];
    const float* bn3g = (const float*)d_in[23], *bn3b = (const float*)d_in[24];
    const float* bn3m = (const float*)d_in[25], *bn3v = (const float*)d_in[26];

    short* wsS = (short*)d_ws;
    __hip_bfloat16* xb    = (__hip_bfloat16*)(wsS + 0);
    __hip_bfloat16* wgcnb = (__hip_bfloat16*)(wsS + 2097152);
    __hip_bfloat16* iwb   = (__hip_bfloat16*)(wsS + 2162688);
    __hip_bfloat16* owb   = (__hip_bfloat16*)(wsS + 2359296);
    __hip_bfloat16* w1b   = (__hip_bfloat16*)(wsS + 2424832);
    __hip_bfloat16* w2b   = (__hip_bfloat16*)(wsS + 2686976);
    short* VtG  = wsS + 2949120;      // 16x8x32x512 bf16 (global V^T)
    short* hlB  = wsS + 5046272;      // 16 x 256 x 512 bf16
    short* x1b  = wsS + 7143424;      // 8192x256
    short* ctxb = wsS + 9240576;      // 8192x256
    short* x2b  = wsS + 11337728;     // 8192x256
    short* h1b  = wsS + 13434880;     // 8192x1024
    short* SAb  = wsS + 21823488;     // 16x512x512 bf16
    float* SA   = (float*)(wsS + 26017792);   // 16x512x512 f32 (dead after conv)
    short* qkvb = wsS + 26017792;             // 8192x768 bf16 (overlaps SA)
    float* out  = (float*)d_out;

    dim3 blk(256);
    // converts of static inputs
    conv6<<<dim3(2880), blk, 0, stream>>>(x, w_gcn, in_w, outw, w1, w2,
                                          xb, wgcnb, iwb, owb, w1b, w2b);
    // dense adjacency
    hipMemsetAsync(SA, 0, (size_t)16 * 512 * 512 * 4, stream);
    build_S<<<dim3(1024), blk, 0, stream>>>(erows, ecols, evals, SA);
    convA<<<dim3(4096), blk, 0, stream>>>(SA, (__hip_bfloat16*)SAb, 1048576);
    // 1. hlB = (xb @ wgcnb^T)^T per graph  (EPI=4, all cols transposed)
    mgemm<64,64,4,1,0><<<dim3(4, 128), blk, 0, stream>>>((const short*)xb, (const short*)wgcnb,
        nullptr, nullptr, NT_, D_, D_, 0,0,0,0, hlB, nullptr, nullptr, nullptr, nullptr);
    // 2. x1 = bn1(x + gelu(S @ hl))  batched per graph (K=512 -> 2 chunks)
    mgemm<64,64,3,1,0><<<dim3(4, 8, 16), blk, 0, stream>>>(SAb, hlB, nullptr, x1b,
        512, D_, 512, 262144, 131072, 131072, 131072,
        x, bn1g, bn1b, bn1m, bn1v);
    // 3. qkv = x1b @ iwb^T + in_b; Q/K cols -> qkvb, V cols -> VtG transposed
    mgemm<64,64,4,1,0><<<dim3(12, 128), blk, 0, stream>>>(x1b, (const short*)iwb, in_b, qkvb,
        NT_, 3 * D_, D_, 0,0,0,512, VtG, nullptr, nullptr, nullptr, nullptr);
    // 4. attention -> ctx (bf16), MFMA
    attn_mfma<<<dim3(1024), blk, 0, stream>>>(qkvb, VtG, (__hip_bfloat16*)ctxb);
    // 5. x2 = bn2(x1 + ctx @ owb^T + outb)
    mgemm<64,64,2,1,1><<<dim3(4, 128), blk, 0, stream>>>(ctxb, (const short*)owb, outb, x2b,
        NT_, D_, D_, 0,0,0,0, x1b, bn2g, bn2b, bn2m, bn2v);
    // 6. h1 = gelu(x2 @ w1b^T + b1)
    mgemm<64,64,1,1,0><<<dim3(16, 128), blk, 0, stream>>>(x2b, (const short*)w1b, b1, h1b,
        NT_, 4 * D_, D_, 0,0,0,0, nullptr, nullptr, nullptr, nullptr, nullptr);
    // 7. out = bn3(x2 + h1 @ w2b^T + b2)   (f32 out, K=1024 -> 4 chunks)
    mgemm<64,64,2,0,1><<<dim3(4, 128), blk, 0, stream>>>(h1b, (const short*)w2b, b2, out,
        NT_, D_, 4 * D_, 0,0,0,0, x2b, bn3g, bn3b, bn3m, bn3v);
}

// Round 11
// 245.000 us; speedup vs baseline: 1.0688x; 1.0688x over previous
//
#include <hip/hip_runtime.h>
#include <hip/hip_bf16.h>
#include <math.h>

#define D_    256
#define NT_   8192
#define NN_   512
#define B_    16
#define H_    8
#define EPG_  16384
#define BN_EPS 1e-5f

typedef __attribute__((ext_vector_type(8))) short bx8;
typedef __attribute__((ext_vector_type(4))) short sx4;
typedef __attribute__((ext_vector_type(4))) float fx4;

__device__ __forceinline__ float gelu_exact(float x) {
    return 0.5f * x * (1.0f + erff(x * 0.70710678118654752f));
}
__device__ __forceinline__ short bf16s(float v) {
    __hip_bfloat16 hb = __float2bfloat16(v);
    return *(short*)&hb;
}

// async global->LDS 16B per lane; lds dest wave-uniform base, gsrc per-lane
typedef __attribute__((address_space(1))) const unsigned int GU;
typedef __attribute__((address_space(3))) unsigned int LU;
__device__ __forceinline__ void gl_lds16(const void* g, void* l) {
    __builtin_amdgcn_global_load_lds((GU*)g, (LU*)l, 16, 0, 0);
}

// ============ bf16 MFMA GEMM: C = A(MxK) @ B(NxK)^T (+bias)(+epi) =========
// BK=64, tile TM x TN, 4 waves (2x2), double-buffered LDS 2-phase prefetch
// (R9 structure: STAGE(next) BEFORE compute(cur), one barrier/iter).
// 16B LDS slots XOR-swizzled by (row&7) on BOTH sides.
// EPI: 0 none, 1 gelu, 2 resid+BN, 3 resid+gelu(acc)+BN,
//      4 transposed-write: cols>=sR packed-4 to Tout(=resid), cols<sR -> Cout
// OBF: output bf16 (else f32). RBF: resid bf16 (else f32).
template<int TM, int TN, int EPI, int OBF, int RBF>
__global__ __launch_bounds__(256)
void mgemm(const short* __restrict__ A, const short* __restrict__ Bw,
           const float* __restrict__ bias, void* __restrict__ Cout,
           int M, int N, int K,
           long sA, long sB, long sC, long sR,
           const void* __restrict__ resid,
           const float* __restrict__ bng, const float* __restrict__ bnb,
           const float* __restrict__ bnm, const float* __restrict__ bnv)
{
    constexpr int MR = TM / 32, NR = TN / 32;   // per-wave 16x16 frags
    constexpr int NIA = TM / 8, NIB = TN / 8;   // 1KiB issues per buffer
    __shared__ short As[2][TM][64];
    __shared__ short Bs[2][TN][64];
    const int bz = blockIdx.z;
    A  += (size_t)bz * sA;
    Bw += (size_t)bz * sB;
    const int bm = blockIdx.y * TM, bn = blockIdx.x * TN;
    const int tid = threadIdx.x;
    const int w = tid >> 6, lane = tid & 63;
    const int wm = w >> 1, wn = w & 1;
    const int fr = lane & 15;
    const int srow = lane >> 3;                               // row within issue
    const int scol = (((lane & 7) ^ (srow & 7)) << 3);        // swizzled src col
    fx4 acc[MR][NR] = {};

    auto STAGE = [&](int buf, int k0) {
        #pragma unroll
        for (int i = w; i < NIA + NIB; i += 4) {
            if (i < NIA)
                gl_lds16(A + (size_t)(bm + i * 8 + srow) * K + k0 + scol,
                         (char*)&As[buf][0][0] + i * 1024);
            else
                gl_lds16(Bw + (size_t)(bn + (i - NIA) * 8 + srow) * K + k0 + scol,
                         (char*)&Bs[buf][0][0] + (i - NIA) * 1024);
        }
    };

    STAGE(0, 0);
    __syncthreads();                       // drain: buf0 ready
    const int T = K >> 6;
    for (int t = 0; t < T; ++t) {
        const int cur = t & 1;
        if (t + 1 < T) STAGE(cur ^ 1, (t + 1) << 6);   // async prefetch
        #pragma unroll
        for (int ks = 0; ks < 2; ++ks) {
            const int sl = (ks << 2) | (lane >> 4);    // logical 16B slot
            bx8 af[MR], bf[NR];
            #pragma unroll
            for (int m = 0; m < MR; ++m) {
                const int row = wm * (TM / 2) + m * 16 + fr;
                af[m] = *(const bx8*)&As[cur][row][(sl ^ (row & 7)) << 3];
            }
            #pragma unroll
            for (int n = 0; n < NR; ++n) {
                const int row = wn * (TN / 2) + n * 16 + fr;
                bf[n] = *(const bx8*)&Bs[cur][row][(sl ^ (row & 7)) << 3];
            }
            #pragma unroll
            for (int m = 0; m < MR; ++m)
                #pragma unroll
                for (int n = 0; n < NR; ++n)
                    acc[m][n] = __builtin_amdgcn_mfma_f32_16x16x32_bf16(af[m], bf[n], acc[m][n], 0, 0, 0);
        }
        __syncthreads();   // one barrier/iter: drains prefetch + protects cur
    }

    float* Cf = (float*)Cout + (size_t)bz * sC;
    __hip_bfloat16* Cb = (__hip_bfloat16*)Cout + (size_t)bz * sC;
    const float* Rf = (const float*)resid + ((EPI == 2 || EPI == 3) ? (size_t)bz * sR : 0);
    const __hip_bfloat16* Rb = (const __hip_bfloat16*)resid + ((EPI == 2 || EPI == 3) ? (size_t)bz * sR : 0);
    #pragma unroll
    for (int m = 0; m < MR; ++m) {
        #pragma unroll
        for (int n = 0; n < NR; ++n) {
            const int gm0 = bm + wm * (TM / 2) + m * 16 + (lane >> 4) * 4;
            const int gn  = bn + wn * (TN / 2) + n * 16 + fr;
            float vv[4];
            #pragma unroll
            for (int r = 0; r < 4; ++r) {
                const int gm = gm0 + r;
                float v = acc[m][n][r];
                if (bias) v += bias[gn];
                if (EPI == 1) v = gelu_exact(v);
                if (EPI == 2 || EPI == 3) {
                    const float rv = RBF ? __bfloat162float(Rb[(size_t)gm * N + gn])
                                         : Rf[(size_t)gm * N + gn];
                    if (EPI == 2) v += rv;
                    else          v = rv + gelu_exact(v);
                    v = (v - bnm[gn]) * (bng[gn] * rsqrtf(bnv[gn] + BN_EPS)) + bnb[gn];
                }
                vv[r] = v;
            }
            if (EPI == 4) {
                const int tc = (int)sR;             // transpose cutoff column
                if (gn >= tc) {
                    short* Tout = (short*)resid;
                    sx4 pk;
                    #pragma unroll
                    for (int r = 0; r < 4; ++r) pk[r] = bf16s(vv[r]);
                    *(sx4*)(Tout + ((size_t)((gm0 >> 9) * (N - tc) + (gn - tc))) * 512 + (gm0 & 511)) = pk;
                } else {
                    #pragma unroll
                    for (int r = 0; r < 4; ++r)
                        Cb[(size_t)(gm0 + r) * N + gn] = __float2bfloat16(vv[r]);
                }
            } else {
                #pragma unroll
                for (int r = 0; r < 4; ++r) {
                    if (OBF) Cb[(size_t)(gm0 + r) * N + gn] = __float2bfloat16(vv[r]);
                    else     Cf[(size_t)(gm0 + r) * N + gn] = vv[r];
                }
            }
        }
    }
}

// ============ converts ======================================================
__device__ __forceinline__ void cv4(const float4 v, __hip_bfloat16* d) {
    __hip_bfloat162* dp = (__hip_bfloat162*)d;
    dp[0] = __hip_bfloat162(__float2bfloat16(v.x), __float2bfloat16(v.y));
    dp[1] = __hip_bfloat162(__float2bfloat16(v.z), __float2bfloat16(v.w));
}

__global__ __launch_bounds__(256)
void conv6(const float* __restrict__ x,  const float* __restrict__ wg,
           const float* __restrict__ iw, const float* __restrict__ ow,
           const float* __restrict__ w1, const float* __restrict__ w2,
           __hip_bfloat16* xb, __hip_bfloat16* wgb, __hip_bfloat16* iwb,
           __hip_bfloat16* owb, __hip_bfloat16* w1b, __hip_bfloat16* w2b)
{
    int i = blockIdx.x * 256 + threadIdx.x;   // float4 index
    const float* s; __hip_bfloat16* d; int o;
    if      (i < 524288) { s = x;  d = xb;  o = i; }
    else if (i < 540672) { s = wg; d = wgb; o = i - 524288; }
    else if (i < 589824) { s = iw; d = iwb; o = i - 540672; }
    else if (i < 606208) { s = ow; d = owb; o = i - 589824; }
    else if (i < 671744) { s = w1; d = w1b; o = i - 606208; }
    else                 { s = w2; d = w2b; o = i - 671744; }
    cv4(((const float4*)s)[o], d + (size_t)o * 4);
}

__global__ __launch_bounds__(256)
void convA(const float* __restrict__ s, __hip_bfloat16* __restrict__ d, int n4)
{
    int i = blockIdx.x * 256 + threadIdx.x;
    if (i >= n4) return;
    cv4(((const float4*)s)[i], d + (size_t)i * 4);
}

// ============ dense adjacency build ========================================
__global__ __launch_bounds__(256)
void build_S(const int* __restrict__ rows, const int* __restrict__ cols,
             const float* __restrict__ vals, float* __restrict__ SA)
{
    const int e = blockIdx.x * 256 + threadIdx.x;   // 262144 edges
    const int r = rows[e], c = cols[e];
    const int g = r >> 9;
    atomicAdd(&SA[((size_t)g << 18) + (size_t)(r & 511) * 512 + (c - (g << 9))], vals[e]);
}

// ============ MFMA flash attention: block = (b, h, 64 q-rows) ==============
// Zero-barrier / zero-staging: K and V fragments read directly from global
// (L2-resident 64KB slab per (b,h), shared by 8 q-tile blocks via XCD
// swizzle). Only LDS use is the wave-local P buffer -> 65KB -> 2 blocks/CU.
__global__ __launch_bounds__(256, 2)
void attn_mfma(const short* __restrict__ qkv, const short* __restrict__ VtG,
               __hip_bfloat16* __restrict__ ctx)
{
    const int swz = (blockIdx.x & 7) * 128 + (blockIdx.x >> 3);
    const int qt = swz & 7;
    const int h  = (swz >> 3) & 7;
    const int b  = swz >> 6;
    __shared__ short Ps[64][520];
    const int tid = threadIdx.x;
    const int lane = tid & 63, wq = tid >> 6;
    const short* base = qkv + (size_t)b * NN_ * 768;
    const short* kb_  = base + 256 + h * 32;
    const short* vtb  = VtG + (size_t)(b * 8 + h) * 32 * 512;

    const int fr = lane & 15, hi = lane >> 4, fk = hi << 3;
    const int qrow = qt * 64 + wq * 16 + fr;
    bx8 qf = *(const bx8*)(base + (size_t)qrow * 768 + h * 32 + fk);

    // S^T tiles: sc[nt] = mfma(K_frag, Q) -> lane holds q=fr, keys nt*16+hi*4+r
    fx4 sc[32];
    #pragma unroll
    for (int nt = 0; nt < 32; ++nt) {
        bx8 kf = *(const bx8*)(kb_ + (size_t)(nt * 16 + fr) * 768 + fk);
        fx4 z = {0.f, 0.f, 0.f, 0.f};
        sc[nt] = __builtin_amdgcn_mfma_f32_16x16x32_bf16(kf, qf, z, 0, 0, 0);
    }

    const float scale = 0.17677669529663687f;   // 1/sqrt(32)
    float mx = -1e30f;
    #pragma unroll
    for (int nt = 0; nt < 32; ++nt)
        mx = fmaxf(mx, fmaxf(fmaxf(sc[nt][0], sc[nt][1]), fmaxf(sc[nt][2], sc[nt][3])));
    mx = fmaxf(mx, __shfl_xor(mx, 16, 64));
    mx = fmaxf(mx, __shfl_xor(mx, 32, 64));
    const float M = mx * scale;
    float s = 0.f;
    #pragma unroll
    for (int nt = 0; nt < 32; ++nt) {
        #pragma unroll
        for (int r = 0; r < 4; ++r) {
            const float p = __expf(sc[nt][r] * scale - M);
            sc[nt][r] = p;
            s += p;
        }
    }
    s += __shfl_xor(s, 16, 64);
    s += __shfl_xor(s, 32, 64);
    const float inv = 1.0f / s;
    {   // P -> LDS: 4 consecutive keys per tile -> one 8B write (wave-local)
        const int q = wq * 16 + fr;
        const int kb2 = hi << 2;
        #pragma unroll
        for (int nt = 0; nt < 32; ++nt) {
            sx4 pk;
            #pragma unroll
            for (int r = 0; r < 4; ++r) pk[r] = bf16s(sc[nt][r] * inv);
            *(sx4*)&Ps[q][nt * 16 + kb2] = pk;
        }
    }

    // O = P @ V : pf from LDS, vf direct from global V^T
    fx4 oacc[2] = {};
    #pragma unroll
    for (int step = 0; step < 16; ++step) {
        bx8 pf = *(const bx8*)&Ps[wq * 16 + fr][step * 32 + fk];
        #pragma unroll
        for (int nt = 0; nt < 2; ++nt) {
            bx8 vf = *(const bx8*)(vtb + (size_t)(nt * 16 + fr) * 512 + step * 32 + fk);
            oacc[nt] = __builtin_amdgcn_mfma_f32_16x16x32_bf16(pf, vf, oacc[nt], 0, 0, 0);
        }
    }
    #pragma unroll
    for (int nt = 0; nt < 2; ++nt) {
        #pragma unroll
        for (int r = 0; r < 4; ++r) {
            const int q = qt * 64 + wq * 16 + hi * 4 + r;
            const int d = nt * 16 + fr;
            ctx[(size_t)(b * NN_ + q) * D_ + h * 32 + d] = __float2bfloat16(oacc[nt][r]);
        }
    }
}

extern "C" void kernel_launch(void* const* d_in, const int* in_sizes, int n_in,
                              void* d_out, int out_size, void* d_ws, size_t ws_size,
                              hipStream_t stream) {
    const float* x      = (const float*)d_in[0];
    const int*   erows  = (const int*)d_in[1];
    const int*   ecols  = (const int*)d_in[2];
    const float* evals  = (const float*)d_in[3];
    const float* w_gcn  = (const float*)d_in[4];
    const float* in_w   = (const float*)d_in[5];
    const float* in_b   = (const float*)d_in[6];
    const float* outw   = (const float*)d_in[7];
    const float* outb   = (const float*)d_in[8];
    const float* w1     = (const float*)d_in[9];
    const float* b1     = (const float*)d_in[10];
    const float* w2     = (const float*)d_in[11];
    const float* b2     = (const float*)d_in[12];
    const float* bn1g = (const float*)d_in[15], *bn1b = (const float*)d_in[16];
    const float* bn1m = (const float*)d_in[17], *bn1v = (const float*)d_in[18];
    const float* bn2g = (const float*)d_in[19], *bn2b = (const float*)d_in[20];
    const float* bn2m = (const float*)d_in[21], *bn2v = (const float*)d_in[22];
    const float* bn3g = (const float*)d_in[23], *bn3b = (const float*)d_in[24];
    const float* bn3m = (const float*)d_in[25], *bn3v = (const float*)d_in[26];

    short* wsS = (short*)d_ws;
    __hip_bfloat16* xb    = (__hip_bfloat16*)(wsS + 0);
    __hip_bfloat16* wgcnb = (__hip_bfloat16*)(wsS + 2097152);
    __hip_bfloat16* iwb   = (__hip_bfloat16*)(wsS + 2162688);
    __hip_bfloat16* owb   = (__hip_bfloat16*)(wsS + 2359296);
    __hip_bfloat16* w1b   = (__hip_bfloat16*)(wsS + 2424832);
    __hip_bfloat16* w2b   = (__hip_bfloat16*)(wsS + 2686976);
    short* VtG  = wsS + 2949120;      // 16x8x32x512 bf16 (global V^T)
    short* hlB  = wsS + 5046272;      // 16 x 256 x 512 bf16
    short* x1b  = wsS + 7143424;      // 8192x256
    short* ctxb = wsS + 9240576;      // 8192x256
    short* x2b  = wsS + 11337728;     // 8192x256
    short* h1b  = wsS + 13434880;     // 8192x1024
    short* SAb  = wsS + 21823488;     // 16x512x512 bf16
    float* SA   = (float*)(wsS + 26017792);   // 16x512x512 f32 (dead after conv)
    short* qkvb = wsS + 26017792;             // 8192x768 bf16 (overlaps SA)
    float* out  = (float*)d_out;

    dim3 blk(256);
    // converts of static inputs
    conv6<<<dim3(2880), blk, 0, stream>>>(x, w_gcn, in_w, outw, w1, w2,
                                          xb, wgcnb, iwb, owb, w1b, w2b);
    // dense adjacency
    hipMemsetAsync(SA, 0, (size_t)16 * 512 * 512 * 4, stream);
    build_S<<<dim3(1024), blk, 0, stream>>>(erows, ecols, evals, SA);
    convA<<<dim3(4096), blk, 0, stream>>>(SA, (__hip_bfloat16*)SAb, 1048576);
    // 1. hlB = (xb @ wgcnb^T)^T per graph  (EPI=4, all cols transposed)
    mgemm<64,64,4,1,0><<<dim3(4, 128), blk, 0, stream>>>((const short*)xb, (const short*)wgcnb,
        nullptr, nullptr, NT_, D_, D_, 0,0,0,0, hlB, nullptr, nullptr, nullptr, nullptr);
    // 2. x1 = bn1(x + gelu(S @ hl))  batched per graph
    mgemm<64,64,3,1,0><<<dim3(4, 8, 16), blk, 0, stream>>>(SAb, hlB, nullptr, x1b,
        512, D_, 512, 262144, 131072, 131072, 131072,
        x, bn1g, bn1b, bn1m, bn1v);
    // 3. qkv = x1b @ iwb^T + in_b; Q/K cols -> qkvb, V cols -> VtG transposed
    mgemm<64,64,4,1,0><<<dim3(12, 128), blk, 0, stream>>>(x1b, (const short*)iwb, in_b, qkvb,
        NT_, 3 * D_, D_, 0,0,0,512, VtG, nullptr, nullptr, nullptr, nullptr);
    // 4. attention -> ctx (bf16), MFMA
    attn_mfma<<<dim3(1024), blk, 0, stream>>>(qkvb, VtG, (__hip_bfloat16*)ctxb);
    // 5. x2 = bn2(x1 + ctx @ owb^T + outb)
    mgemm<64,64,2,1,1><<<dim3(4, 128), blk, 0, stream>>>(ctxb, (const short*)owb, outb, x2b,
        NT_, D_, D_, 0,0,0,0, x1b, bn2g, bn2b, bn2m, bn2v);
    // 6. h1 = gelu(x2 @ w1b^T + b1)
    mgemm<64,64,1,1,0><<<dim3(16, 128), blk, 0, stream>>>(x2b, (const short*)w1b, b1, h1b,
        NT_, 4 * D_, D_, 0,0,0,0, nullptr, nullptr, nullptr, nullptr, nullptr);
    // 7. out = bn3(x2 + h1 @ w2b^T + b2)   (f32 out)
    mgemm<64,64,2,0,1><<<dim3(4, 128), blk, 0, stream>>>(h1b, (const short*)w2b, b2, out,
        NT_, D_, 4 * D_, 0,0,0,0, x2b, bn3g, bn3b, bn3m, bn3v);
}

// Round 12
// 222.927 us; speedup vs baseline: 1.1746x; 1.0990x over previous
//
#include <hip/hip_runtime.h>
#include <hip/hip_bf16.h>
#include <math.h>

#define D_    256
#define NT_   8192
#define NN_   512
#define B_    16
#define H_    8
#define EPG_  16384
#define BN_EPS 1e-5f

typedef __attribute__((ext_vector_type(8))) short bx8;
typedef __attribute__((ext_vector_type(4))) short sx4;
typedef __attribute__((ext_vector_type(4))) float fx4;

__device__ __forceinline__ float gelu_exact(float x) {
    return 0.5f * x * (1.0f + erff(x * 0.70710678118654752f));
}
__device__ __forceinline__ short bf16s(float v) {
    __hip_bfloat16 hb = __float2bfloat16(v);
    return *(short*)&hb;
}

// async global->LDS 16B per lane; lds dest wave-uniform base, gsrc per-lane
typedef __attribute__((address_space(1))) const unsigned int GU;
typedef __attribute__((address_space(3))) unsigned int LU;
__device__ __forceinline__ void gl_lds16(const void* g, void* l) {
    __builtin_amdgcn_global_load_lds((GU*)g, (LU*)l, 16, 0, 0);
}

// ============ bf16 MFMA GEMM: C = A(MxK) @ B(NxK)^T (+bias)(+epi) =========
// BK=64, tile TM x TN, 4 waves (2x2), double-buffered LDS 2-phase prefetch.
// XCD-affinity remap: XCD X (= wg%8, HW round-robin) always owns row-blocks
// [X*NY/8, (X+1)*NY/8) -- consistent across ALL GEMMs + attn, so each
// activation row is produced and consumed in the same per-XCD L2.
// 16B LDS slots XOR-swizzled by (row&7) on BOTH sides.
// EPI: 0 none, 1 gelu, 2 resid+BN, 3 resid+gelu(acc)+BN,
//      4 transposed-write: cols>=sR packed-4 to Tout(=resid), cols<sR -> Cout
// OBF: output bf16 (else f32). RBF: resid bf16 (else f32).
template<int TM, int TN, int EPI, int OBF, int RBF>
__global__ __launch_bounds__(256)
void mgemm(const short* __restrict__ A, const short* __restrict__ Bw,
           const float* __restrict__ bias, void* __restrict__ Cout,
           int M, int N, int K,
           long sA, long sB, long sC, long sR,
           const void* __restrict__ resid,
           const float* __restrict__ bng, const float* __restrict__ bnb,
           const float* __restrict__ bnm, const float* __restrict__ bnv)
{
    constexpr int MR = TM / 32, NR = TN / 32;   // per-wave 16x16 frags
    constexpr int NIA = TM / 8, NIB = TN / 8;   // 1KiB issues per buffer
    __shared__ short As[2][TM][64];
    __shared__ short Bs[2][TN][64];
    // --- XCD-affinity block remap (requires (nx*ny*nz) % 8 == 0) ---
    const int nx = gridDim.x, ny = gridDim.y, nzz = gridDim.z;
    const int NY = ny * nzz;
    const int wg = blockIdx.x + nx * (blockIdx.y + ny * blockIdx.z);
    const int X  = wg & 7, rr = wg >> 3;
    const int bph = NY >> 3;
    const int bxl = rr % nx;
    const int ry  = X * bph + rr / nx;
    const int byl = ry % ny;
    const int bz  = ry / ny;
    A  += (size_t)bz * sA;
    Bw += (size_t)bz * sB;
    const int bm = byl * TM, bn = bxl * TN;
    const int tid = threadIdx.x;
    const int w = tid >> 6, lane = tid & 63;
    const int wm = w >> 1, wn = w & 1;
    const int fr = lane & 15;
    const int srow = lane >> 3;                               // row within issue
    const int scol = (((lane & 7) ^ (srow & 7)) << 3);        // swizzled src col
    fx4 acc[MR][NR] = {};

    auto STAGE = [&](int buf, int k0) {
        #pragma unroll
        for (int i = w; i < NIA + NIB; i += 4) {
            if (i < NIA)
                gl_lds16(A + (size_t)(bm + i * 8 + srow) * K + k0 + scol,
                         (char*)&As[buf][0][0] + i * 1024);
            else
                gl_lds16(Bw + (size_t)(bn + (i - NIA) * 8 + srow) * K + k0 + scol,
                         (char*)&Bs[buf][0][0] + (i - NIA) * 1024);
        }
    };

    STAGE(0, 0);
    __syncthreads();                       // drain: buf0 ready
    const int T = K >> 6;
    for (int t = 0; t < T; ++t) {
        const int cur = t & 1;
        if (t + 1 < T) STAGE(cur ^ 1, (t + 1) << 6);   // async prefetch
        #pragma unroll
        for (int ks = 0; ks < 2; ++ks) {
            const int sl = (ks << 2) | (lane >> 4);    // logical 16B slot
            bx8 af[MR], bf[NR];
            #pragma unroll
            for (int m = 0; m < MR; ++m) {
                const int row = wm * (TM / 2) + m * 16 + fr;
                af[m] = *(const bx8*)&As[cur][row][(sl ^ (row & 7)) << 3];
            }
            #pragma unroll
            for (int n = 0; n < NR; ++n) {
                const int row = wn * (TN / 2) + n * 16 + fr;
                bf[n] = *(const bx8*)&Bs[cur][row][(sl ^ (row & 7)) << 3];
            }
            #pragma unroll
            for (int m = 0; m < MR; ++m)
                #pragma unroll
                for (int n = 0; n < NR; ++n)
                    acc[m][n] = __builtin_amdgcn_mfma_f32_16x16x32_bf16(af[m], bf[n], acc[m][n], 0, 0, 0);
        }
        __syncthreads();   // one barrier/iter: drains prefetch + protects cur
    }

    float* Cf = (float*)Cout + (size_t)bz * sC;
    __hip_bfloat16* Cb = (__hip_bfloat16*)Cout + (size_t)bz * sC;
    const float* Rf = (const float*)resid + ((EPI == 2 || EPI == 3) ? (size_t)bz * sR : 0);
    const __hip_bfloat16* Rb = (const __hip_bfloat16*)resid + ((EPI == 2 || EPI == 3) ? (size_t)bz * sR : 0);
    #pragma unroll
    for (int m = 0; m < MR; ++m) {
        #pragma unroll
        for (int n = 0; n < NR; ++n) {
            const int gm0 = bm + wm * (TM / 2) + m * 16 + (lane >> 4) * 4;
            const int gn  = bn + wn * (TN / 2) + n * 16 + fr;
            float vv[4];
            #pragma unroll
            for (int r = 0; r < 4; ++r) {
                const int gm = gm0 + r;
                float v = acc[m][n][r];
                if (bias) v += bias[gn];
                if (EPI == 1) v = gelu_exact(v);
                if (EPI == 2 || EPI == 3) {
                    const float rv = RBF ? __bfloat162float(Rb[(size_t)gm * N + gn])
                                         : Rf[(size_t)gm * N + gn];
                    if (EPI == 2) v += rv;
                    else          v = rv + gelu_exact(v);
                    v = (v - bnm[gn]) * (bng[gn] * rsqrtf(bnv[gn] + BN_EPS)) + bnb[gn];
                }
                vv[r] = v;
            }
            if (EPI == 4) {
                const int tc = (int)sR;             // transpose cutoff column
                if (gn >= tc) {
                    short* Tout = (short*)resid;
                    sx4 pk;
                    #pragma unroll
                    for (int r = 0; r < 4; ++r) pk[r] = bf16s(vv[r]);
                    *(sx4*)(Tout + ((size_t)((gm0 >> 9) * (N - tc) + (gn - tc))) * 512 + (gm0 & 511)) = pk;
                } else {
                    #pragma unroll
                    for (int r = 0; r < 4; ++r)
                        Cb[(size_t)(gm0 + r) * N + gn] = __float2bfloat16(vv[r]);
                }
            } else {
                #pragma unroll
                for (int r = 0; r < 4; ++r) {
                    if (OBF) Cb[(size_t)(gm0 + r) * N + gn] = __float2bfloat16(vv[r]);
                    else     Cf[(size_t)(gm0 + r) * N + gn] = vv[r];
                }
            }
        }
    }
}

// ============ converts ======================================================
__device__ __forceinline__ void cv4(const float4 v, __hip_bfloat16* d) {
    __hip_bfloat162* dp = (__hip_bfloat162*)d;
    dp[0] = __hip_bfloat162(__float2bfloat16(v.x), __float2bfloat16(v.y));
    dp[1] = __hip_bfloat162(__float2bfloat16(v.z), __float2bfloat16(v.w));
}

__global__ __launch_bounds__(256)
void conv6(const float* __restrict__ x,  const float* __restrict__ wg,
           const float* __restrict__ iw, const float* __restrict__ ow,
           const float* __restrict__ w1, const float* __restrict__ w2,
           __hip_bfloat16* xb, __hip_bfloat16* wgb, __hip_bfloat16* iwb,
           __hip_bfloat16* owb, __hip_bfloat16* w1b, __hip_bfloat16* w2b)
{
    int i = blockIdx.x * 256 + threadIdx.x;   // float4 index
    const float* s; __hip_bfloat16* d; int o;
    if      (i < 524288) { s = x;  d = xb;  o = i; }
    else if (i < 540672) { s = wg; d = wgb; o = i - 524288; }
    else if (i < 589824) { s = iw; d = iwb; o = i - 540672; }
    else if (i < 606208) { s = ow; d = owb; o = i - 589824; }
    else if (i < 671744) { s = w1; d = w1b; o = i - 606208; }
    else                 { s = w2; d = w2b; o = i - 671744; }
    cv4(((const float4*)s)[o], d + (size_t)o * 4);
}

__global__ __launch_bounds__(256)
void convA(const float* __restrict__ s, __hip_bfloat16* __restrict__ d, int n4)
{
    int i = blockIdx.x * 256 + threadIdx.x;
    if (i >= n4) return;
    cv4(((const float4*)s)[i], d + (size_t)i * 4);
}

// ============ dense adjacency build ========================================
__global__ __launch_bounds__(256)
void build_S(const int* __restrict__ rows, const int* __restrict__ cols,
             const float* __restrict__ vals, float* __restrict__ SA)
{
    const int e = blockIdx.x * 256 + threadIdx.x;   // 262144 edges
    const int r = rows[e], c = cols[e];
    const int g = r >> 9;
    atomicAdd(&SA[((size_t)g << 18) + (size_t)(r & 511) * 512 + (c - (g << 9))], vals[e]);
}

// ============ MFMA flash attention: block = (b, h, 64 q-rows) ==============
// Staged (R9 structure): K rows + V^T rows in LDS, one barrier; swapped QK^T
// so softmax is per-lane + 2 shuffles; P packed -> ds_write_b64.
// XCD swizzle: graph b -> XCD b/2 (rows [X*1024,(X+1)*1024) -- matches mgemm).
__global__ __launch_bounds__(256, 1)
void attn_mfma(const short* __restrict__ qkv, const short* __restrict__ VtG,
               __hip_bfloat16* __restrict__ ctx)
{
    const int swz = (blockIdx.x & 7) * 128 + (blockIdx.x >> 3);
    const int qt = swz & 7;
    const int h  = (swz >> 3) & 7;
    const int b  = swz >> 6;
    __shared__ short Ks[512][40];
    __shared__ short Vt[32][520];
    __shared__ short Ps[64][520];
    const int tid = threadIdx.x;
    const int lane = tid & 63, wq = tid >> 6;
    const short* base = qkv + (size_t)b * NN_ * 768;
    const short* vtb  = VtG + (size_t)(b * 8 + h) * 32 * 512;

    {   // stage K rows (vectorized)
        const int d0 = (tid & 3) << 3;
        const int k0 = tid >> 2;
        #pragma unroll
        for (int rep = 0; rep < 8; ++rep) {
            const int key = k0 + rep * 64;
            *(bx8*)&Ks[key][d0] =
                *(const bx8*)(base + (size_t)key * 768 + 256 + h * 32 + d0);
        }
    }
    {   // stage Vt rows from precomputed global V^T (fully vectorized)
        const int d = tid >> 3, c0 = (tid & 7) << 3;
        #pragma unroll
        for (int rep = 0; rep < 8; ++rep) {
            const int c = c0 + rep * 64;
            *(bx8*)&Vt[d][c] = *(const bx8*)(vtb + (size_t)d * 512 + c);
        }
    }
    const int fr = lane & 15, hi = lane >> 4, fk = hi << 3;
    const int qrow = qt * 64 + wq * 16 + fr;
    bx8 qf = *(const bx8*)(base + (size_t)qrow * 768 + h * 32 + fk);
    __syncthreads();

    // S^T tiles: sc[nt] = mfma(K_tile, Q) -> lane holds q=fr, keys nt*16+hi*4+r
    fx4 sc[32];
    #pragma unroll
    for (int nt = 0; nt < 32; ++nt) {
        bx8 kf = *(const bx8*)&Ks[nt * 16 + fr][fk];
        fx4 z = {0.f, 0.f, 0.f, 0.f};
        sc[nt] = __builtin_amdgcn_mfma_f32_16x16x32_bf16(kf, qf, z, 0, 0, 0);
    }

    const float scale = 0.17677669529663687f;   // 1/sqrt(32)
    float mx = -1e30f;
    #pragma unroll
    for (int nt = 0; nt < 32; ++nt)
        mx = fmaxf(mx, fmaxf(fmaxf(sc[nt][0], sc[nt][1]), fmaxf(sc[nt][2], sc[nt][3])));
    mx = fmaxf(mx, __shfl_xor(mx, 16, 64));
    mx = fmaxf(mx, __shfl_xor(mx, 32, 64));
    const float M = mx * scale;
    float s = 0.f;
    #pragma unroll
    for (int nt = 0; nt < 32; ++nt) {
        #pragma unroll
        for (int r = 0; r < 4; ++r) {
            const float p = __expf(sc[nt][r] * scale - M);
            sc[nt][r] = p;
            s += p;
        }
    }
    s += __shfl_xor(s, 16, 64);
    s += __shfl_xor(s, 32, 64);
    const float inv = 1.0f / s;
    {   // P -> LDS: 4 consecutive keys per tile -> one 8B write (wave-local)
        const int q = wq * 16 + fr;
        const int kb2 = hi << 2;
        #pragma unroll
        for (int nt = 0; nt < 32; ++nt) {
            sx4 pk;
            #pragma unroll
            for (int r = 0; r < 4; ++r) pk[r] = bf16s(sc[nt][r] * inv);
            *(sx4*)&Ps[q][nt * 16 + kb2] = pk;
        }
    }

    // O = P @ V
    fx4 oacc[2] = {};
    #pragma unroll
    for (int step = 0; step < 16; ++step) {
        bx8 pf = *(const bx8*)&Ps[wq * 16 + fr][step * 32 + fk];
        #pragma unroll
        for (int nt = 0; nt < 2; ++nt) {
            bx8 vf = *(const bx8*)&Vt[nt * 16 + fr][step * 32 + fk];
            oacc[nt] = __builtin_amdgcn_mfma_f32_16x16x32_bf16(pf, vf, oacc[nt], 0, 0, 0);
        }
    }
    #pragma unroll
    for (int nt = 0; nt < 2; ++nt) {
        #pragma unroll
        for (int r = 0; r < 4; ++r) {
            const int q = qt * 64 + wq * 16 + hi * 4 + r;
            const int d = nt * 16 + fr;
            ctx[(size_t)(b * NN_ + q) * D_ + h * 32 + d] = __float2bfloat16(oacc[nt][r]);
        }
    }
}

extern "C" void kernel_launch(void* const* d_in, const int* in_sizes, int n_in,
                              void* d_out, int out_size, void* d_ws, size_t ws_size,
                              hipStream_t stream) {
    const float* x      = (const float*)d_in[0];
    const int*   erows  = (const int*)d_in[1];
    const int*   ecols  = (const int*)d_in[2];
    const float* evals  = (const float*)d_in[3];
    const float* w_gcn  = (const float*)d_in[4];
    const float* in_w   = (const float*)d_in[5];
    const float* in_b   = (const float*)d_in[6];
    const float* outw   = (const float*)d_in[7];
    const float* outb   = (const float*)d_in[8];
    const float* w1     = (const float*)d_in[9];
    const float* b1     = (const float*)d_in[10];
    const float* w2     = (const float*)d_in[11];
    const float* b2     = (const float*)d_in[12];
    const float* bn1g = (const float*)d_in[15], *bn1b = (const float*)d_in[16];
    const float* bn1m = (const float*)d_in[17], *bn1v = (const float*)d_in[18];
    const float* bn2g = (const float*)d_in[19], *bn2b = (const float*)d_in[20];
    const float* bn2m = (const float*)d_in[21], *bn2v = (const float*)d_in[22];
    const float* bn3g = (const float*)d_in[23], *bn3b = (const float*)d_in[24];
    const float* bn3m = (const float*)d_in[25], *bn3v = (const float*)d_in[26];

    short* wsS = (short*)d_ws;
    __hip_bfloat16* xb    = (__hip_bfloat16*)(wsS + 0);
    __hip_bfloat16* wgcnb = (__hip_bfloat16*)(wsS + 2097152);
    __hip_bfloat16* iwb   = (__hip_bfloat16*)(wsS + 2162688);
    __hip_bfloat16* owb   = (__hip_bfloat16*)(wsS + 2359296);
    __hip_bfloat16* w1b   = (__hip_bfloat16*)(wsS + 2424832);
    __hip_bfloat16* w2b   = (__hip_bfloat16*)(wsS + 2686976);
    short* VtG  = wsS + 2949120;      // 16x8x32x512 bf16 (global V^T)
    short* hlB  = wsS + 5046272;      // 16 x 256 x 512 bf16
    short* x1b  = wsS + 7143424;      // 8192x256
    short* ctxb = wsS + 9240576;      // 8192x256
    short* x2b  = wsS + 11337728;     // 8192x256
    short* h1b  = wsS + 13434880;     // 8192x1024
    short* SAb  = wsS + 21823488;     // 16x512x512 bf16
    float* SA   = (float*)(wsS + 26017792);   // 16x512x512 f32 (dead after conv)
    short* qkvb = wsS + 26017792;             // 8192x768 bf16 (overlaps SA)
    float* out  = (float*)d_out;

    dim3 blk(256);
    // converts of static inputs
    conv6<<<dim3(2880), blk, 0, stream>>>(x, w_gcn, in_w, outw, w1, w2,
                                          xb, wgcnb, iwb, owb, w1b, w2b);
    // dense adjacency
    hipMemsetAsync(SA, 0, (size_t)16 * 512 * 512 * 4, stream);
    build_S<<<dim3(1024), blk, 0, stream>>>(erows, ecols, evals, SA);
    convA<<<dim3(4096), blk, 0, stream>>>(SA, (__hip_bfloat16*)SAb, 1048576);
    // 1. hlB = (xb @ wgcnb^T)^T per graph  (EPI=4, all cols transposed)
    mgemm<64,64,4,1,0><<<dim3(4, 128), blk, 0, stream>>>((const short*)xb, (const short*)wgcnb,
        nullptr, nullptr, NT_, D_, D_, 0,0,0,0, hlB, nullptr, nullptr, nullptr, nullptr);
    // 2. x1 = bn1(x + gelu(S @ hl))  batched per graph
    mgemm<64,64,3,1,0><<<dim3(4, 8, 16), blk, 0, stream>>>(SAb, hlB, nullptr, x1b,
        512, D_, 512, 262144, 131072, 131072, 131072,
        x, bn1g, bn1b, bn1m, bn1v);
    // 3. qkv = x1b @ iwb^T + in_b; Q/K cols -> qkvb, V cols -> VtG transposed
    mgemm<64,64,4,1,0><<<dim3(12, 128), blk, 0, stream>>>(x1b, (const short*)iwb, in_b, qkvb,
        NT_, 3 * D_, D_, 0,0,0,512, VtG, nullptr, nullptr, nullptr, nullptr);
    // 4. attention -> ctx (bf16), MFMA
    attn_mfma<<<dim3(1024), blk, 0, stream>>>(qkvb, VtG, (__hip_bfloat16*)ctxb);
    // 5. x2 = bn2(x1 + ctx @ owb^T + outb)
    mgemm<64,64,2,1,1><<<dim3(4, 128), blk, 0, stream>>>(ctxb, (const short*)owb, outb, x2b,
        NT_, D_, D_, 0,0,0,0, x1b, bn2g, bn2b, bn2m, bn2v);
    // 6. h1 = gelu(x2 @ w1b^T + b1)
    mgemm<64,64,1,1,0><<<dim3(16, 128), blk, 0, stream>>>(x2b, (const short*)w1b, b1, h1b,
        NT_, 4 * D_, D_, 0,0,0,0, nullptr, nullptr, nullptr, nullptr, nullptr);
    // 7. out = bn3(x2 + h1 @ w2b^T + b2)   (f32 out)
    mgemm<64,64,2,0,1><<<dim3(4, 128), blk, 0, stream>>>(h1b, (const short*)w2b, b2, out,
        NT_, D_, 4 * D_, 0,0,0,0, x2b, bn3g, bn3b, bn3m, bn3v);
}